// Round 1
// baseline (136.605 us; speedup 1.0000x reference)
//
#include <hip/hip_runtime.h>
#include <hip/hip_bf16.h>

#define G_ 8
#define GIN_ 256
#define GOUT_ 256
#define NROWS_ 8192
#define LDX_ 2048   // = G_*GIN_ = row stride of x and out

typedef __attribute__((ext_vector_type(4))) float f32x4;
typedef __attribute__((ext_vector_type(8))) short bf16x8;

// ---------------------------------------------------------------------------
// LDS-only barrier: __syncthreads() on gfx950 drains vmcnt(0) (ALL in-flight
// global stores + loads) before s_barrier — a multi-thousand-cycle stall per
// slab when 8 waves x 16 stores are in flight. Correctness here only needs
// each wave's LDS ops retired (lgkmcnt) before the exec barrier; global
// stores need no ordering and prefetch loads are consumed by their own wave
// (compiler emits a counted vmcnt before use). Fused single asm so nothing
// is scheduled between the waitcnt and the barrier; "memory" clobber stops
// the compiler moving LDS accesses across it.
// ---------------------------------------------------------------------------
__device__ __forceinline__ void lds_barrier() {
    asm volatile("s_waitcnt lgkmcnt(0)\n\ts_barrier" ::: "memory");
}

// ---------------------------------------------------------------------------
// Prep: W [G][GIN][GOUT] f32  ->  Wt [G][GOUT][GIN] bf16 (transposed+converted)
// Grid: 128 blocks x 256 threads. LDS-tiled transpose: coalesced both ways.
// ---------------------------------------------------------------------------
__global__ __launch_bounds__(256) void wprep_kernel(const float* __restrict__ W,
                                                    __hip_bfloat16* __restrict__ Wt) {
    __shared__ float tile[64][65];   // +1 pad: conflict-free transposed read
    const int bid = blockIdx.x;
    const int g  = bid >> 4;
    const int ot = (bid >> 2) & 3;   // o-tile (64 wide)
    const int it = bid & 3;          // i-tile (64 wide)
    const float* Wg = W + g * GIN_ * GOUT_;
    __hip_bfloat16* Wtg = Wt + g * GIN_ * GOUT_;
    const int lane_o = threadIdx.x & 63;
    const int sub    = threadIdx.x >> 6;   // 0..3
#pragma unroll
    for (int r = 0; r < 16; ++r) {
        int i = r * 4 + sub;
        tile[i][lane_o] = Wg[(it * 64 + i) * GOUT_ + ot * 64 + lane_o];
    }
    __syncthreads();
#pragma unroll
    for (int r = 0; r < 16; ++r) {
        int o = r * 4 + sub;
        Wtg[(ot * 64 + o) * GIN_ + it * 64 + lane_o] = __float2bfloat16(tile[lane_o][o]);
    }
}

// ---------------------------------------------------------------------------
// Main fused kernel — traffic-minimal: x is read from global EXACTLY ONCE.
//  Block = 512 threads (8 waves), covers the FULL 256-col width of one group
//  for a 128-row range (4 slabs of 32 rows).
//  - B: per-wave 32 cols x full K=256 in REGISTERS (64 VGPRs).
//  - A: 32-row x-slab staged f32->bf16 into LDS (16 KB), double-buffered,
//    BROADCAST to all 8 waves.
//  - LDS layout: row stride 512 B, 16B-granule XOR swizzle (gh ^ (row&7)).
//  - One LDS-ONLY barrier per slab (no vmcnt drain — stores stay in flight);
//    next slab's global loads are issued BEFORE the MFMA loop so compute
//    covers their latency.
// Grid: 8 groups x 64 row-blocks = 512 blocks; bid&7 = g -> W[g] L2-local.
// ---------------------------------------------------------------------------
__global__ __launch_bounds__(512, 4) void gkan_kernel(const float* __restrict__ x,
                                                      const __hip_bfloat16* __restrict__ Wt,
                                                      const float* __restrict__ bias,
                                                      const float* __restrict__ pc,
                                                      const float* __restrict__ qc,
                                                      float* __restrict__ out) {
    __shared__ __align__(16) __hip_bfloat16 As[2][32 * 256];   // 2 x 16 KB

    const int bid    = blockIdx.x;
    const int g      = bid & 7;
    const int mblock = bid >> 3;        // 0..63
    const int row0   = mblock * 128;

    const int t    = threadIdx.x;
    const int wave = t >> 6;            // 0..7 -> cols [wave*32, +32)
    const int lane = t & 63;
    const int lm   = lane & 15;
    const int quad = lane >> 4;

    // ---- B: register-resident, wave's 32 cols x K=256 (64 VGPRs) ----
    bf16x8 Breg[2][8];
    {
        const __hip_bfloat16* Wg = Wt + (size_t)g * (GIN_ * GOUT_)
                                      + (size_t)(wave * 32) * GIN_;
#pragma unroll
        for (int nt = 0; nt < 2; ++nt)
#pragma unroll
            for (int c = 0; c < 8; ++c)
                Breg[nt][c] = *(const bf16x8*)(Wg + (size_t)(nt * 16 + lm) * GIN_
                                                  + c * 32 + quad * 8);
    }

    // ---- per-lane constants (hoisted out of the slab loop) ----
    const float p0 = pc[g * 4 + 0], p1 = pc[g * 4 + 1];
    const float p2 = pc[g * 4 + 2], p3 = pc[g * 4 + 3];
    const float q0 = qc[g * 3 + 0], q1 = qc[g * 3 + 1], q2 = qc[g * 3 + 2];
    float bb[2];
#pragma unroll
    for (int nt = 0; nt < 2; ++nt)
        bb[nt] = bias[g * GOUT_ + wave * 32 + nt * 16 + lm];

    // ---- staging geometry: thread owns 16 f32 of one slab row ----
    const int sr = t >> 4;              // 0..31  slab row
    const int su = t & 15;              // 0..15  32B unit within row
    const float* xs = x + (size_t)(row0 + sr) * LDX_ + g * GIN_ + su * 16;
    const int go0 = (((2 * su)     ^ (sr & 7)) * 8);   // swizzled bf16 offsets
    const int go1 = (((2 * su + 1) ^ (sr & 7)) * 8);
    __hip_bfloat16* row_b0 = &As[0][sr * 256];
    __hip_bfloat16* row_b1 = &As[1][sr * 256];

    f32x4 st0, st1, st2, st3;
    st0 = *(const f32x4*)(xs);
    st1 = *(const f32x4*)(xs + 4);
    st2 = *(const f32x4*)(xs + 8);
    st3 = *(const f32x4*)(xs + 12);
    {
        union { __hip_bfloat16 h[8]; bf16x8 v; } ca, cb;
        ca.h[0] = __float2bfloat16(st0.x); ca.h[1] = __float2bfloat16(st0.y);
        ca.h[2] = __float2bfloat16(st0.z); ca.h[3] = __float2bfloat16(st0.w);
        ca.h[4] = __float2bfloat16(st1.x); ca.h[5] = __float2bfloat16(st1.y);
        ca.h[6] = __float2bfloat16(st1.z); ca.h[7] = __float2bfloat16(st1.w);
        cb.h[0] = __float2bfloat16(st2.x); cb.h[1] = __float2bfloat16(st2.y);
        cb.h[2] = __float2bfloat16(st2.z); cb.h[3] = __float2bfloat16(st2.w);
        cb.h[4] = __float2bfloat16(st3.x); cb.h[5] = __float2bfloat16(st3.y);
        cb.h[6] = __float2bfloat16(st3.z); cb.h[7] = __float2bfloat16(st3.w);
        *(bf16x8*)(row_b0 + go0) = ca.v;
        *(bf16x8*)(row_b0 + go1) = cb.v;
    }
    lds_barrier();

#pragma unroll 1
    for (int s = 0; s < 4; ++s) {
        // prefetch next slab's x (issued before compute; vmcnt hidden by MFMA)
        if (s < 3) {
            const float* xn = xs + (size_t)(s + 1) * 32 * LDX_;
            st0 = *(const f32x4*)(xn);
            st1 = *(const f32x4*)(xn + 4);
            st2 = *(const f32x4*)(xn + 8);
            st3 = *(const f32x4*)(xn + 12);
        }

        // ---- compute slab s ----
        const __hip_bfloat16* slab = As[s & 1];
        f32x4 acc[2][2] = {};
#pragma unroll
        for (int c = 0; c < 8; ++c) {
            bf16x8 af[2];
#pragma unroll
            for (int mt = 0; mt < 2; ++mt) {
                const int gh = (c * 4 + quad) ^ (lm & 7);
                af[mt] = *(const bf16x8*)(slab + (mt * 16 + lm) * 256 + gh * 8);
            }
#pragma unroll
            for (int mt = 0; mt < 2; ++mt)
#pragma unroll
                for (int nt = 0; nt < 2; ++nt)
                    acc[mt][nt] = __builtin_amdgcn_mfma_f32_16x16x32_bf16(
                        af[mt], Breg[nt][c], acc[mt][nt], 0, 0, 0);
        }

        // ---- epilogue for slab s: bias + rational, coalesced stores ----
#pragma unroll
        for (int nt = 0; nt < 2; ++nt) {
            const int col = g * GOUT_ + wave * 32 + nt * 16 + lm;
#pragma unroll
            for (int mt = 0; mt < 2; ++mt)
#pragma unroll
                for (int r = 0; r < 4; ++r) {
                    const int row = row0 + s * 32 + mt * 16 + quad * 4 + r;
                    const float y   = acc[mt][nt][r] + bb[nt];
                    const float num = p0 + y * (p1 + y * (p2 + y * p3));
                    const float den = 1.0f + fabsf(y * (q0 + y * (q1 + y * q2)));
                    out[(size_t)row * LDX_ + col] = num * __builtin_amdgcn_rcpf(den);
                }
        }

        // ---- convert + write next slab into the other buffer ----
        if (s < 3) {
            __hip_bfloat16* dst = (s & 1) ? row_b0 : row_b1;
            union { __hip_bfloat16 h[8]; bf16x8 v; } ca, cb;
            ca.h[0] = __float2bfloat16(st0.x); ca.h[1] = __float2bfloat16(st0.y);
            ca.h[2] = __float2bfloat16(st0.z); ca.h[3] = __float2bfloat16(st0.w);
            ca.h[4] = __float2bfloat16(st1.x); ca.h[5] = __float2bfloat16(st1.y);
            ca.h[6] = __float2bfloat16(st1.z); ca.h[7] = __float2bfloat16(st1.w);
            cb.h[0] = __float2bfloat16(st2.x); cb.h[1] = __float2bfloat16(st2.y);
            cb.h[2] = __float2bfloat16(st2.z); cb.h[3] = __float2bfloat16(st2.w);
            cb.h[4] = __float2bfloat16(st3.x); cb.h[5] = __float2bfloat16(st3.y);
            cb.h[6] = __float2bfloat16(st3.z); cb.h[7] = __float2bfloat16(st3.w);
            *(bf16x8*)(dst + go0) = ca.v;
            *(bf16x8*)(dst + go1) = cb.v;
            lds_barrier();
        }
    }
}

extern "C" void kernel_launch(void* const* d_in, const int* in_sizes, int n_in,
                              void* d_out, int out_size, void* d_ws, size_t ws_size,
                              hipStream_t stream) {
    const float* x = (const float*)d_in[0];
    const float* W = (const float*)d_in[1];
    const float* b = (const float*)d_in[2];
    const float* p = (const float*)d_in[3];
    const float* q = (const float*)d_in[4];
    float* out = (float*)d_out;

    __hip_bfloat16* Wt = (__hip_bfloat16*)d_ws;   // 1 MiB bf16 transposed W

    wprep_kernel<<<128, 256, 0, stream>>>(W, Wt);
    gkan_kernel<<<512, 512, 0, stream>>>(x, Wt, b, p, q, out);
}